// Round 16
// baseline (154.855 us; speedup 1.0000x reference)
//
#include <hip/hip_runtime.h>

#define DIM 1024
#define HEADS 16
#define HDIM 64
#define SEQ 2048
// 0.125 * log2(e) — folded into A's projection epilogue
#define SCLOG2 0.18033688011112042f

typedef __attribute__((ext_vector_type(8))) short short8;
typedef __attribute__((ext_vector_type(4))) float f32x4;
typedef __attribute__((ext_vector_type(16))) float f32x16;
typedef __attribute__((ext_vector_type(4))) int i32x4;

static __device__ __forceinline__ unsigned short f2bf(float f){
  union { float f; unsigned int u; } v; v.f = f;
  unsigned int r = v.u + 0x7fffu + ((v.u >> 16) & 1u);
  return (unsigned short)(r >> 16);
}

static __device__ __forceinline__ int cvtpk(float lo, float hi){
  int r;
  asm("v_cvt_pk_bf16_f32 %0, %1, %2" : "=v"(r) : "v"(lo), "v"(hi));
  return r;
}
static __device__ __forceinline__ void swap32(int& a, int& b){
  asm("v_permlane32_swap_b32 %0, %1" : "+v"(a), "+v"(b));
}

__device__ __forceinline__ void gl_lds16(const unsigned short* g, unsigned short* l){
  __builtin_amdgcn_global_load_lds((const __attribute__((address_space(1))) void*)g,
                                   (__attribute__((address_space(3))) void*)l, 16, 0, 0);
}

// ---------------- fused cast: all 5 inputs -> contiguous bf16 ws (HBM-peak, done) ------
#define CAST_TOTAL 3145728

__global__ __launch_bounds__(256)
void cast_all(const float* __restrict__ x, const float* __restrict__ x2,
              const float* __restrict__ wq, const float* __restrict__ wa,
              const float* __restrict__ wkv, unsigned short* __restrict__ out)
{
  for (int i = blockIdx.x*256 + threadIdx.x; i < CAST_TOTAL; i += gridDim.x*256){
    const float* src; int off;
    if      (i < 1048576){ src = x;   off = i; }
    else if (i < 2097152){ src = x2;  off = i - 1048576; }
    else if (i < 2359296){ src = wq;  off = i - 2097152; }
    else if (i < 2621440){ src = wa;  off = i - 2359296; }
    else                 { src = wkv; off = i - 2621440; }
    float4 v = ((const float4*)src)[off];
    ushort4 o;
    o.x = f2bf(v.x); o.y = f2bf(v.y); o.z = f2bf(v.z); o.w = f2bf(v.w);
    ((ushort4*)out)[i] = o;
  }
}

// ---------------- merged GEMM (R12-proven: dbuf + XOR swizzle + XCD stripes) — UNCHANGED
#define GK 1024

__global__ __launch_bounds__(256)
void gemm_all(const unsigned short* __restrict__ xb,  const unsigned short* __restrict__ x2b,
              const unsigned short* __restrict__ Wqb, const unsigned short* __restrict__ Wab,
              const unsigned short* __restrict__ Wkvb,
              unsigned short* __restrict__ Qw, unsigned short* __restrict__ Aw,
              unsigned short* __restrict__ Kw, unsigned short* __restrict__ Vwt)
{
  __shared__ unsigned short Ald[2][128*64];   // 32 KB
  __shared__ unsigned short Bld[2][128*64];   // 32 KB
  const int tid  = threadIdx.x;
  const int lane = tid & 63;
  const int wid  = tid >> 6;
  const int l15 = lane & 15, l4 = lane >> 4;
  const int wm = wid >> 1, wn = wid & 1;

  const int bid = blockIdx.x;
  const unsigned short *Abuf, *Bbuf;
  int mbase, nbase, isA;
  if (bid < 768){
    int xcd = bid & 7, s = bid >> 3;       // s 0..95
    int mb = xcd*4 + (s & 3);              // 0..31, disjoint stripes per XCD
    int nb = s >> 2;                       // 0..23
    nbase = nb*128; mbase = mb*128; isA = 0;
    Abuf = xb;
    Bbuf = (nbase < 1024) ? (Wqb + (size_t)nbase*GK) : (Wkvb + (size_t)(nbase-1024)*GK);
  } else {
    int b2 = bid - 768;                    // 0..255
    int xcd = b2 & 7, s = b2 >> 3;         // s 0..31
    int mb = xcd*4 + (s & 3);
    int nb = s >> 2;                       // 0..7
    nbase = nb*128; mbase = mb*128; isA = 1;
    Abuf = x2b;
    Bbuf = Wab + (size_t)nbase*GK;
  }
  const bool isV = (!isA) && (nbase >= 2048);

  const int srow = wid*32 + (lane >> 3);
  const int scol = ((lane & 7) ^ (lane >> 3)) * 8;   // pre-swizzled source column
  const unsigned short* gA = Abuf + (size_t)(mbase + srow)*GK + scol;
  const unsigned short* gB = Bbuf + (size_t)srow*GK + scol;

  const int rsw = (l15 & 7) * 8;

  f32x4 acc[4][4];
  #pragma unroll
  for (int i=0;i<4;i++)
    #pragma unroll
    for(int j=0;j<4;j++) acc[i][j] = (f32x4){0.f,0.f,0.f,0.f};

  #pragma unroll
  for (int i=0;i<4;++i){
    gl_lds16(gA + (size_t)(i*8)*GK, &Ald[0][(wid*32 + i*8)*64]);
    gl_lds16(gB + (size_t)(i*8)*GK, &Bld[0][(wid*32 + i*8)*64]);
  }
  asm volatile("s_waitcnt vmcnt(0)" ::: "memory");
  __builtin_amdgcn_s_barrier();
  __builtin_amdgcn_sched_barrier(0);

  for (int t = 0; t < 16; ++t){
    const int cur = t & 1;
    if (t+1 < 16){
      const int nxt = cur ^ 1;
      const int kt = (t+1)*64;
      #pragma unroll
      for (int i=0;i<4;++i){
        gl_lds16(gA + (size_t)(i*8)*GK + kt, &Ald[nxt][(wid*32 + i*8)*64]);
        gl_lds16(gB + (size_t)(i*8)*GK + kt, &Bld[nxt][(wid*32 + i*8)*64]);
      }
    }
    #pragma unroll
    for (int kc = 0; kc < 2; ++kc){
      short8 af[4], bf[4];
      #pragma unroll
      for (int mt=0; mt<4; ++mt)
        af[mt] = *(const short8*)(&Ald[cur][(wm*64 + mt*16 + l15)*64 + ((kc*32 + l4*8) ^ rsw)]);
      #pragma unroll
      for (int nt=0; nt<4; ++nt)
        bf[nt] = *(const short8*)(&Bld[cur][(wn*64 + nt*16 + l15)*64 + ((kc*32 + l4*8) ^ rsw)]);
      __builtin_amdgcn_s_setprio(1);
      if (isV){
        #pragma unroll
        for (int mt=0; mt<4; ++mt)
          #pragma unroll
          for (int nt=0; nt<4; ++nt)
            acc[mt][nt] = __builtin_amdgcn_mfma_f32_16x16x32_bf16(af[mt], bf[nt], acc[mt][nt], 0,0,0);
      } else {
        #pragma unroll
        for (int mt=0; mt<4; ++mt)
          #pragma unroll
          for (int nt=0; nt<4; ++nt)
            acc[mt][nt] = __builtin_amdgcn_mfma_f32_16x16x32_bf16(bf[nt], af[mt], acc[mt][nt], 0,0,0);
      }
      __builtin_amdgcn_s_setprio(0);
    }
    asm volatile("s_waitcnt vmcnt(0)" ::: "memory");
    __builtin_amdgcn_s_barrier();
    __builtin_amdgcn_sched_barrier(0);
  }

  if (!isV){
    unsigned short* dst = isA ? Aw : (nbase < 1024 ? Qw : Kw);
    const int coff = (!isA && nbase >= 1024) ? 1024 : 0;
    const float scale = isA ? SCLOG2 : 1.0f;
    #pragma unroll
    for (int mt=0; mt<4; ++mt){
      int token = mbase + wm*64 + mt*16 + l15;
      int b = token >> 11, n = token & 2047;
      #pragma unroll
      for (int nt=0; nt<4; ++nt){
        int colb = nbase - coff + wn*64 + nt*16 + l4*4;
        int h = colb >> 6, d = colb & 63;
        ushort4 pk;
        pk.x = f2bf(acc[mt][nt][0] * scale);
        pk.y = f2bf(acc[mt][nt][1] * scale);
        pk.z = f2bf(acc[mt][nt][2] * scale);
        pk.w = f2bf(acc[mt][nt][3] * scale);
        *(ushort4*)(dst + ((size_t)((b*HEADS + h)*SEQ + n))*HDIM + d) = pk;
      }
    }
  } else {
    #pragma unroll
    for (int mt=0; mt<4; ++mt){
      int mrow = mbase + wm*64 + mt*16 + l4*4;
      int b = mrow >> 11, nblk = mrow & 2047;
      #pragma unroll
      for (int nt=0; nt<4; ++nt){
        int col = nbase + wn*64 + nt*16 + l15;
        int c2 = col - 2048, h = c2 >> 6, d = c2 & 63;
        ushort4 pk;
        pk.x = f2bf(acc[mt][nt][0]);
        pk.y = f2bf(acc[mt][nt][1]);
        pk.z = f2bf(acc[mt][nt][2]);
        pk.w = f2bf(acc[mt][nt][3]);
        *(ushort4*)(Vwt + ((size_t)((b*HEADS + h)*HDIM + d))*SEQ + nblk) = pk;
      }
    }
  }
}

// ---------------- fused flash attention: 2-stage software pipeline ----------------------
// 8 waves: qw = wid&3 (32 q-rows each), kvh = wid>>2 (keys kvh*1024..+1024, 32 tiles of 32)
// Pipeline per iter t: {prefetch t+2 | exp/rowsum of tile t | vmcnt(2)+barrier |
//                       QK(t+1) MFMA  ||  cvtpk + PV(t) MFMA}
// Rowsum on VALU (4 partial chains) + final shfl_xor — no ones-MFMA (20% fewer MFMAs).
// mode 0: writes Y^T [bh][d][q] bf16. mode 1: writes fp32 out[b][q][h*64+d].
#define KT2 32
#define NTH 32     // tiles per kv half

#define ATTN_BODY(T, SCUR, SNEXT)                                                     \
  {                                                                                   \
    const int t_ = (T);                                                               \
    if (t_+2 < NTH){                                                                  \
      const int pb_ = ((t_+2) & 3) * 4096;                                            \
      gl_lds16(gsrc[0] + (size_t)(t_+2)*sstep, SH + ldst[0] + pb_);                   \
      gl_lds16(gsrc[1] + (size_t)(t_+2)*sstep, SH + ldst[1] + pb_);                   \
    }                                                                                 \
    float p_[16];                                                                     \
    _Pragma("unroll")                                                                 \
    for (int r=0;r<16;++r){ p_[r] = __builtin_amdgcn_exp2f(SCUR[r]); os[r&3] += p_[r]; } \
    if (t_+2 < NTH){ asm volatile("s_waitcnt vmcnt(2)" ::: "memory"); }               \
    else if (t_+1 < NTH){ asm volatile("s_waitcnt vmcnt(0)" ::: "memory"); }          \
    __builtin_amdgcn_s_barrier();                                                     \
    __builtin_amdgcn_sched_barrier(0);                                                \
    const unsigned short* Kc_ = SH + grpoff + ((t_+1) & 3)*4096;                      \
    const unsigned short* Vc_ = SH + grpoff + (t_ & 3)*4096 + 2048;                   \
    __builtin_amdgcn_s_setprio(1);                                                    \
    if (t_+1 < NTH){                                                                  \
      _Pragma("unroll")                                                               \
      for (int r=0;r<16;++r) SNEXT[r]=0.f;                                            \
      _Pragma("unroll")                                                               \
      for (int db=0; db<4; ++db){                                                     \
        short8 kfr = *(const short8*)(Kc_ + db*512 + lane*8);                         \
        SNEXT = __builtin_amdgcn_mfma_f32_32x32x16_bf16(kfr, qf[db], SNEXT, 0,0,0);   \
      }                                                                               \
    }                                                                                 \
    _Pragma("unroll")                                                                 \
    for (int kb2=0; kb2<2; ++kb2){                                                    \
      const int pb2 = kb2*8;                                                          \
      int a0 = cvtpk(p_[pb2+0], p_[pb2+1]);                                           \
      int b0 = cvtpk(p_[pb2+4], p_[pb2+5]);                                           \
      int a1 = cvtpk(p_[pb2+2], p_[pb2+3]);                                           \
      int b1 = cvtpk(p_[pb2+6], p_[pb2+7]);                                           \
      swap32(a0, b0); swap32(a1, b1);                                                 \
      i32x4 pav; pav[0]=a0; pav[1]=a1; pav[2]=b0; pav[3]=b1;                          \
      short8 paf = *(short8*)&pav;                                                    \
      short8 v0 = *(const short8*)(Vc_ + (0*2+kb2)*512 + lane*8);                     \
      oo0 = __builtin_amdgcn_mfma_f32_32x32x16_bf16(v0, paf, oo0, 0,0,0);             \
      short8 v1 = *(const short8*)(Vc_ + (1*2+kb2)*512 + lane*8);                     \
      oo1 = __builtin_amdgcn_mfma_f32_32x32x16_bf16(v1, paf, oo1, 0,0,0);             \
    }                                                                                 \
    __builtin_amdgcn_s_setprio(0);                                                    \
  }

__global__ __launch_bounds__(512)
void attn_pass(const unsigned short* __restrict__ Qb,
               const unsigned short* __restrict__ Kb,
               const unsigned short* __restrict__ Vtb,
               unsigned short* __restrict__ ytb,
               float* __restrict__ outf,
               int mode)
{
  // staging: 2 groups x 4 bufs x 4096 shorts = 64 KB; merge overlay Of[128][68]f + Os[128]f
  __shared__ __align__(16) char SHRAW[65536];
  unsigned short* SH = (unsigned short*)SHRAW;
  const int tid = threadIdx.x, lane = tid & 63, wid = tid >> 6;  // 8 waves
  const int l31 = lane & 31, l5 = lane >> 5;
  const int qw = wid & 3, kvh = wid >> 2;

  // XCD-aware decode: 4 bh per XCD, all 16 q-blocks of a bh on one XCD
  const int bid = blockIdx.x;
  const int cx = bid & 7, j = bid >> 3;
  const int bh = cx*4 + (j >> 4);
  const int qb = j & 15;
  const int q0 = qb*128 + qw*32;               // this wave's 32 q-rows
  const size_t base = (size_t)bh * SEQ * HDIM;

  // Q^T B-fragments (col q = l31, k-rows d = db*16 + l5*8 ..+8)
  short8 qf[4];
  #pragma unroll
  for (int db=0; db<4; ++db)
    qf[db] = *(const short8*)(Qb + base + (size_t)(q0 + l31)*HDIM + db*16 + l5*8);

  // staging duty: qw0,1 -> K frags db {0,1},{2,3}; qw2,3 -> V frags (db2*2+kb2)
  const unsigned short* gsrc[2];
  int ldst[2];
  int sstep;
  const int grpoff = kvh * 16384;               // shorts: 4 bufs x 4096
  if (qw < 2){
    #pragma unroll
    for (int f=0; f<2; ++f){
      gsrc[f] = Kb + base + (size_t)(kvh*1024 + l31)*HDIM + (qw*2 + f)*16 + l5*8;
      ldst[f] = grpoff + (qw*2 + f)*512;
    }
    sstep = KT2*HDIM;
  } else {
    const int db2 = qw - 2;
    #pragma unroll
    for (int f=0; f<2; ++f){
      gsrc[f] = Vtb + base + (size_t)(db2*32 + l31)*SEQ + kvh*1024 + f*16 + l5*8;
      ldst[f] = grpoff + 2048 + (db2*2 + f)*512;
    }
    sstep = KT2;
  }

  f32x16 oo0, oo1;
  #pragma unroll
  for (int r=0;r<16;++r){ oo0[r]=0.f; oo1[r]=0.f; }
  float os[4] = {0.f, 0.f, 0.f, 0.f};

  // prologue: stage tiles 0,1 into bufs 0,1; wait tile 0 (vmcnt(2)); QK(0) -> sA
  #pragma unroll
  for (int b=0; b<2; ++b){
    gl_lds16(gsrc[0] + (size_t)b*sstep, SH + ldst[0] + b*4096);
    gl_lds16(gsrc[1] + (size_t)b*sstep, SH + ldst[1] + b*4096);
  }
  asm volatile("s_waitcnt vmcnt(2)" ::: "memory");
  __builtin_amdgcn_s_barrier();
  __builtin_amdgcn_sched_barrier(0);

  f32x16 sA, sB;
  {
    #pragma unroll
    for (int r=0;r<16;++r) sA[r]=0.f;
    const unsigned short* Kc0 = SH + grpoff;
    #pragma unroll
    for (int db=0; db<4; ++db){
      short8 kfr = *(const short8*)(Kc0 + db*512 + lane*8);
      sA = __builtin_amdgcn_mfma_f32_32x32x16_bf16(kfr, qf[db], sA, 0,0,0);
    }
  }

  for (int tt = 0; tt < NTH; tt += 2){
    ATTN_BODY(tt,   sA, sB);
    ATTN_BODY(tt+1, sB, sA);
  }
  __syncthreads();   // all PV reads done before merge overlay writes

  // rowsum finalize: lane l and l^32 hold complementary key halves of the same q
  float osum = (os[0]+os[1]) + (os[2]+os[3]);
  osum += __shfl_xor(osum, 32);

  // ---- in-block merge of the two kv halves ----
  float* Of  = (float*)SHRAW;                 // [128][68]
  float* Os1 = (float*)(SHRAW + 128*68*4);    // [128]
  const int ql = qw*32 + l31;

  if (kvh == 1){
    #pragma unroll
    for (int g=0; g<4; ++g){
      f32x4 w0, w1;
      #pragma unroll
      for (int r=0;r<4;++r){ w0[r] = oo0[g*4+r]; w1[r] = oo1[g*4+r]; }
      int d0 = 8*g + 4*l5;
      *(f32x4*)(Of + ql*68 + d0)      = w0;
      *(f32x4*)(Of + ql*68 + d0 + 32) = w1;
    }
    Os1[ql] = osum;
  }
  __syncthreads();

  if (kvh == 0){
    const float rinv = 1.0f / (osum + Os1[ql]);
    if (mode == 0){
      #pragma unroll
      for (int r=0;r<16;++r){
        int d0 = (r&3) + 8*(r>>2) + 4*l5;
        float f0 = (oo0[r] + Of[ql*68 + d0])      * rinv;
        float f1 = (oo1[r] + Of[ql*68 + d0 + 32]) * rinv;
        ytb[base + (size_t)(d0)*SEQ + q0 + l31]    = f2bf(f0);
        ytb[base + (size_t)(d0+32)*SEQ + q0 + l31] = f2bf(f1);
      }
    } else {
      #pragma unroll
      for (int g=0; g<4; ++g){
        int d0 = 8*g + 4*l5;
        f32x4 w0 = *(const f32x4*)(Of + ql*68 + d0);
        f32x4 w1 = *(const f32x4*)(Of + ql*68 + d0 + 32);
        #pragma unroll
        for (int r=0;r<4;++r){ w0[r] = (w0[r]+oo0[g*4+r])*rinv; w1[r] = (w1[r]+oo1[g*4+r])*rinv; }
        *(f32x4*)(Of + ql*68 + d0)      = w0;
        *(f32x4*)(Of + ql*68 + d0 + 32) = w1;
      }
    }
  }

  if (mode == 1){
    __syncthreads();
    const int b = bh >> 4, h = bh & 15;
    const int qr = tid >> 2, dh = (tid & 3)*16;
    const float* src = Of + qr*68 + dh;
    float* drow = outf + ((size_t)(b*SEQ + qb*128 + qr))*DIM + h*HDIM + dh;
    #pragma unroll
    for (int k2=0;k2<4;++k2)
      *(float4*)(drow + k2*4) = *(const float4*)(src + k2*4);
  }
}

extern "C" void kernel_launch(void* const* d_in, const int* in_sizes, int n_in,
                              void* d_out, int out_size, void* d_ws, size_t ws_size,
                              hipStream_t stream) {
  const float* x   = (const float*)d_in[0];
  const float* x2  = (const float*)d_in[1];
  const float* Wq  = (const float*)d_in[2];
  const float* Wa  = (const float*)d_in[3];
  const float* Wkv = (const float*)d_in[4];
  float* out = (float*)d_out;

  unsigned short* ws = (unsigned short*)d_ws;
  unsigned short* xb   = ws;                      // 4096*1024
  unsigned short* x2b  = xb   + 4096*1024;
  unsigned short* Wqb  = x2b  + 4096*1024;        // 1024*1024
  unsigned short* Wab  = Wqb  + 1024*1024;
  unsigned short* Wkvb = Wab  + 1024*1024;        // 2048*1024
  unsigned short* Qw   = Wkvb + 2048*1024;        // BHND = 4194304 each
  unsigned short* Aw   = Qw   + 4194304;
  unsigned short* Kw   = Aw   + 4194304;
  unsigned short* Vwt  = Kw   + 4194304;          // V^T [bh][d][n] (direct from gemm)
  unsigned short* Ywt  = xb;                      // Y^T [bh][d][n] (xb dead after gemm)

  cast_all<<<dim3(3072), dim3(256), 0, stream>>>(x, x2, Wq, Wa, Wkv, ws);

  gemm_all<<<dim3(1024), dim3(256), 0, stream>>>(xb, x2b, Wqb, Wab, Wkvb, Qw, Aw, Kw, Vwt);

  // pass 1: Y^T = (softmax(A k^T s) v)^T  -- written directly transposed
  attn_pass<<<dim3(512), dim3(512), 0, stream>>>(Aw, Kw, Vwt, Ywt, nullptr, 0);

  // pass 2: out = softmax(q A^T s) Y
  attn_pass<<<dim3(512), dim3(512), 0, stream>>>(Qw, Aw, Ywt, nullptr, out, 1);
}

// Round 17
// 146.731 us; speedup vs baseline: 1.0554x; 1.0554x over previous
//
#include <hip/hip_runtime.h>

#define DIM 1024
#define HEADS 16
#define HDIM 64
#define SEQ 2048
// 0.125 * log2(e) — folded into A's projection epilogue
#define SCLOG2 0.18033688011112042f

typedef __attribute__((ext_vector_type(8))) short short8;
typedef __attribute__((ext_vector_type(4))) float f32x4;
typedef __attribute__((ext_vector_type(16))) float f32x16;
typedef __attribute__((ext_vector_type(4))) int i32x4;

static __device__ __forceinline__ unsigned short f2bf(float f){
  union { float f; unsigned int u; } v; v.f = f;
  unsigned int r = v.u + 0x7fffu + ((v.u >> 16) & 1u);
  return (unsigned short)(r >> 16);
}

static __device__ __forceinline__ int cvtpk(float lo, float hi){
  int r;
  asm("v_cvt_pk_bf16_f32 %0, %1, %2" : "=v"(r) : "v"(lo), "v"(hi));
  return r;
}
static __device__ __forceinline__ void swap32(int& a, int& b){
  asm("v_permlane32_swap_b32 %0, %1" : "+v"(a), "+v"(b));
}

__device__ __forceinline__ void gl_lds16(const unsigned short* g, unsigned short* l){
  __builtin_amdgcn_global_load_lds((const __attribute__((address_space(1))) void*)g,
                                   (__attribute__((address_space(3))) void*)l, 16, 0, 0);
}

// ---------------- fused cast: all 5 inputs -> contiguous bf16 ws (HBM-peak, done) ------
#define CAST_TOTAL 3145728

__global__ __launch_bounds__(256)
void cast_all(const float* __restrict__ x, const float* __restrict__ x2,
              const float* __restrict__ wq, const float* __restrict__ wa,
              const float* __restrict__ wkv, unsigned short* __restrict__ out)
{
  for (int i = blockIdx.x*256 + threadIdx.x; i < CAST_TOTAL; i += gridDim.x*256){
    const float* src; int off;
    if      (i < 1048576){ src = x;   off = i; }
    else if (i < 2097152){ src = x2;  off = i - 1048576; }
    else if (i < 2359296){ src = wq;  off = i - 2097152; }
    else if (i < 2621440){ src = wa;  off = i - 2359296; }
    else                 { src = wkv; off = i - 2621440; }
    float4 v = ((const float4*)src)[off];
    ushort4 o;
    o.x = f2bf(v.x); o.y = f2bf(v.y); o.z = f2bf(v.z); o.w = f2bf(v.w);
    ((ushort4*)out)[i] = o;
  }
}

// ---------------- merged GEMM (R12-proven: dbuf + XOR swizzle + XCD stripes) — UNCHANGED
#define GK 1024

__global__ __launch_bounds__(256)
void gemm_all(const unsigned short* __restrict__ xb,  const unsigned short* __restrict__ x2b,
              const unsigned short* __restrict__ Wqb, const unsigned short* __restrict__ Wab,
              const unsigned short* __restrict__ Wkvb,
              unsigned short* __restrict__ Qw, unsigned short* __restrict__ Aw,
              unsigned short* __restrict__ Kw, unsigned short* __restrict__ Vwt)
{
  __shared__ unsigned short Ald[2][128*64];   // 32 KB
  __shared__ unsigned short Bld[2][128*64];   // 32 KB
  const int tid  = threadIdx.x;
  const int lane = tid & 63;
  const int wid  = tid >> 6;
  const int l15 = lane & 15, l4 = lane >> 4;
  const int wm = wid >> 1, wn = wid & 1;

  const int bid = blockIdx.x;
  const unsigned short *Abuf, *Bbuf;
  int mbase, nbase, isA;
  if (bid < 768){
    int xcd = bid & 7, s = bid >> 3;       // s 0..95
    int mb = xcd*4 + (s & 3);              // 0..31, disjoint stripes per XCD
    int nb = s >> 2;                       // 0..23
    nbase = nb*128; mbase = mb*128; isA = 0;
    Abuf = xb;
    Bbuf = (nbase < 1024) ? (Wqb + (size_t)nbase*GK) : (Wkvb + (size_t)(nbase-1024)*GK);
  } else {
    int b2 = bid - 768;                    // 0..255
    int xcd = b2 & 7, s = b2 >> 3;         // s 0..31
    int mb = xcd*4 + (s & 3);
    int nb = s >> 2;                       // 0..7
    nbase = nb*128; mbase = mb*128; isA = 1;
    Abuf = x2b;
    Bbuf = Wab + (size_t)nbase*GK;
  }
  const bool isV = (!isA) && (nbase >= 2048);

  const int srow = wid*32 + (lane >> 3);
  const int scol = ((lane & 7) ^ (lane >> 3)) * 8;   // pre-swizzled source column
  const unsigned short* gA = Abuf + (size_t)(mbase + srow)*GK + scol;
  const unsigned short* gB = Bbuf + (size_t)srow*GK + scol;

  const int rsw = (l15 & 7) * 8;

  f32x4 acc[4][4];
  #pragma unroll
  for (int i=0;i<4;i++)
    #pragma unroll
    for(int j=0;j<4;j++) acc[i][j] = (f32x4){0.f,0.f,0.f,0.f};

  #pragma unroll
  for (int i=0;i<4;++i){
    gl_lds16(gA + (size_t)(i*8)*GK, &Ald[0][(wid*32 + i*8)*64]);
    gl_lds16(gB + (size_t)(i*8)*GK, &Bld[0][(wid*32 + i*8)*64]);
  }
  asm volatile("s_waitcnt vmcnt(0)" ::: "memory");
  __builtin_amdgcn_s_barrier();
  __builtin_amdgcn_sched_barrier(0);

  for (int t = 0; t < 16; ++t){
    const int cur = t & 1;
    if (t+1 < 16){
      const int nxt = cur ^ 1;
      const int kt = (t+1)*64;
      #pragma unroll
      for (int i=0;i<4;++i){
        gl_lds16(gA + (size_t)(i*8)*GK + kt, &Ald[nxt][(wid*32 + i*8)*64]);
        gl_lds16(gB + (size_t)(i*8)*GK + kt, &Bld[nxt][(wid*32 + i*8)*64]);
      }
    }
    #pragma unroll
    for (int kc = 0; kc < 2; ++kc){
      short8 af[4], bf[4];
      #pragma unroll
      for (int mt=0; mt<4; ++mt)
        af[mt] = *(const short8*)(&Ald[cur][(wm*64 + mt*16 + l15)*64 + ((kc*32 + l4*8) ^ rsw)]);
      #pragma unroll
      for (int nt=0; nt<4; ++nt)
        bf[nt] = *(const short8*)(&Bld[cur][(wn*64 + nt*16 + l15)*64 + ((kc*32 + l4*8) ^ rsw)]);
      __builtin_amdgcn_s_setprio(1);
      if (isV){
        #pragma unroll
        for (int mt=0; mt<4; ++mt)
          #pragma unroll
          for (int nt=0; nt<4; ++nt)
            acc[mt][nt] = __builtin_amdgcn_mfma_f32_16x16x32_bf16(af[mt], bf[nt], acc[mt][nt], 0,0,0);
      } else {
        #pragma unroll
        for (int mt=0; mt<4; ++mt)
          #pragma unroll
          for (int nt=0; nt<4; ++nt)
            acc[mt][nt] = __builtin_amdgcn_mfma_f32_16x16x32_bf16(bf[nt], af[mt], acc[mt][nt], 0,0,0);
      }
      __builtin_amdgcn_s_setprio(0);
    }
    asm volatile("s_waitcnt vmcnt(0)" ::: "memory");
    __builtin_amdgcn_s_barrier();
    __builtin_amdgcn_sched_barrier(0);
  }

  if (!isV){
    unsigned short* dst = isA ? Aw : (nbase < 1024 ? Qw : Kw);
    const int coff = (!isA && nbase >= 1024) ? 1024 : 0;
    const float scale = isA ? SCLOG2 : 1.0f;
    #pragma unroll
    for (int mt=0; mt<4; ++mt){
      int token = mbase + wm*64 + mt*16 + l15;
      int b = token >> 11, n = token & 2047;
      #pragma unroll
      for (int nt=0; nt<4; ++nt){
        int colb = nbase - coff + wn*64 + nt*16 + l4*4;
        int h = colb >> 6, d = colb & 63;
        ushort4 pk;
        pk.x = f2bf(acc[mt][nt][0] * scale);
        pk.y = f2bf(acc[mt][nt][1] * scale);
        pk.z = f2bf(acc[mt][nt][2] * scale);
        pk.w = f2bf(acc[mt][nt][3] * scale);
        *(ushort4*)(dst + ((size_t)((b*HEADS + h)*SEQ + n))*HDIM + d) = pk;
      }
    }
  } else {
    #pragma unroll
    for (int mt=0; mt<4; ++mt){
      int mrow = mbase + wm*64 + mt*16 + l4*4;
      int b = mrow >> 11, nblk = mrow & 2047;
      #pragma unroll
      for (int nt=0; nt<4; ++nt){
        int col = nbase + wn*64 + nt*16 + l15;
        int c2 = col - 2048, h = c2 >> 6, d = c2 & 63;
        ushort4 pk;
        pk.x = f2bf(acc[mt][nt][0]);
        pk.y = f2bf(acc[mt][nt][1]);
        pk.z = f2bf(acc[mt][nt][2]);
        pk.w = f2bf(acc[mt][nt][3]);
        *(ushort4*)(Vwt + ((size_t)((b*HEADS + h)*HDIM + d))*SEQ + nblk) = pk;
      }
    }
  }
}

// ---------------- fused flash attention: R13 body, 2 tiles per barrier, VALU rowsum ----
// 8 waves: qw = wid&3 (32 q-rows each), kvh = wid>>2 (keys kvh*1024..+1024, 32 tiles of 32)
// 4 LDS bufs/group; interval i computes tiles {2i,2i+1} (buf pair (i&1)*2) while staging
// tiles {2i+2,2i+3} into the other pair; ONE vmcnt(0)+barrier per interval (16 barriers).
// Rowsum on VALU (4 partial chains) + final shfl_xor(32) — MFMA/tile 10 -> 8.
// mode 0: writes Y^T [bh][d][q] bf16. mode 1: writes fp32 out[b][q][h*64+d].
#define KT2 32
#define NTH 32     // tiles per kv half

__global__ __launch_bounds__(512)
void attn_pass(const unsigned short* __restrict__ Qb,
               const unsigned short* __restrict__ Kb,
               const unsigned short* __restrict__ Vtb,
               unsigned short* __restrict__ ytb,
               float* __restrict__ outf,
               int mode)
{
  // staging: 2 groups x 4 bufs x 4096 shorts = 64 KB; merge overlay Of[128][68]f + Os[128]f
  __shared__ __align__(16) char SHRAW[65536];
  unsigned short* SH = (unsigned short*)SHRAW;
  const int tid = threadIdx.x, lane = tid & 63, wid = tid >> 6;  // 8 waves
  const int l31 = lane & 31, l5 = lane >> 5;
  const int qw = wid & 3, kvh = wid >> 2;

  // XCD-aware decode: 4 bh per XCD, all 16 q-blocks of a bh on one XCD
  const int bid = blockIdx.x;
  const int cx = bid & 7, j = bid >> 3;
  const int bh = cx*4 + (j >> 4);
  const int qb = j & 15;
  const int q0 = qb*128 + qw*32;               // this wave's 32 q-rows
  const size_t base = (size_t)bh * SEQ * HDIM;

  // Q^T B-fragments (col q = l31, k-rows d = db*16 + l5*8 ..+8)
  short8 qf[4];
  #pragma unroll
  for (int db=0; db<4; ++db)
    qf[db] = *(const short8*)(Qb + base + (size_t)(q0 + l31)*HDIM + db*16 + l5*8);

  // staging duty: qw0,1 -> K frags db {0,1},{2,3}; qw2,3 -> V frags (db2*2+kb2)
  const unsigned short* gsrc[2];
  int ldst[2];
  int sstep;
  const int grpoff = kvh * 16384;               // shorts: 4 bufs x 4096
  if (qw < 2){
    #pragma unroll
    for (int f=0; f<2; ++f){
      gsrc[f] = Kb + base + (size_t)(kvh*1024 + l31)*HDIM + (qw*2 + f)*16 + l5*8;
      ldst[f] = grpoff + (qw*2 + f)*512;
    }
    sstep = KT2*HDIM;
  } else {
    const int db2 = qw - 2;
    #pragma unroll
    for (int f=0; f<2; ++f){
      gsrc[f] = Vtb + base + (size_t)(db2*32 + l31)*SEQ + kvh*1024 + f*16 + l5*8;
      ldst[f] = grpoff + 2048 + (db2*2 + f)*512;
    }
    sstep = KT2;
  }

  f32x16 oo0, oo1;
  #pragma unroll
  for (int r=0;r<16;++r){ oo0[r]=0.f; oo1[r]=0.f; }
  float os[4] = {0.f, 0.f, 0.f, 0.f};

  // prologue: stage tiles 0,1 into bufs 0,1
  #pragma unroll
  for (int b=0; b<2; ++b)
    #pragma unroll
    for (int f=0; f<2; ++f)
      gl_lds16(gsrc[f] + (size_t)b*sstep, SH + ldst[f] + b*4096);
  asm volatile("s_waitcnt vmcnt(0)" ::: "memory");
  __builtin_amdgcn_s_barrier();
  __builtin_amdgcn_sched_barrier(0);

  for (int i = 0; i < 16; ++i){
    const int pairBase = (i & 1) * 8192;        // bufs holding tiles 2i, 2i+1
    if (i < 15){
      const int stBase = pairBase ^ 8192;       // opposite pair for tiles 2i+2, 2i+3
      #pragma unroll
      for (int u=0; u<2; ++u)
        #pragma unroll
        for (int f=0; f<2; ++f)
          gl_lds16(gsrc[f] + (size_t)(2*i+2+u)*sstep, SH + ldst[f] + stBase + u*4096);
    }

    #pragma unroll
    for (int u=0; u<2; ++u){
      const unsigned short* Kc = SH + grpoff + pairBase + u*4096;
      const unsigned short* Vc = Kc + 2048;

      // S^T = K * Q^T : lane = col q0+l31, rows key = (r&3)+8*(r>>2)+4*l5 (32-key tile)
      f32x16 sacc;
      #pragma unroll
      for (int r=0;r<16;++r) sacc[r]=0.f;
      __builtin_amdgcn_s_setprio(1);
      #pragma unroll
      for (int db=0; db<4; ++db){
        short8 kfr = *(const short8*)(Kc + db*512 + lane*8);
        sacc = __builtin_amdgcn_mfma_f32_32x32x16_bf16(kfr, qf[db], sacc, 0,0,0);
      }
      __builtin_amdgcn_s_setprio(0);
      float p[16];
      #pragma unroll
      for (int r=0;r<16;++r){
        p[r] = __builtin_amdgcn_exp2f(sacc[r]);   // scale pre-folded into A projection
        os[r & 3] += p[r];                         // 4 independent partial-sum chains
      }

      // build P^T B-frags in registers; PV
      #pragma unroll
      for (int kb2=0; kb2<2; ++kb2){
        const int pb2 = kb2*8;
        int a0 = cvtpk(p[pb2+0], p[pb2+1]);
        int b0 = cvtpk(p[pb2+4], p[pb2+5]);
        int a1 = cvtpk(p[pb2+2], p[pb2+3]);
        int b1 = cvtpk(p[pb2+6], p[pb2+7]);
        swap32(a0, b0);
        swap32(a1, b1);
        i32x4 pav; pav[0]=a0; pav[1]=a1; pav[2]=b0; pav[3]=b1;
        short8 paf = *(short8*)&pav;
        __builtin_amdgcn_s_setprio(1);
        short8 v0 = *(const short8*)(Vc + (0*2+kb2)*512 + lane*8);
        oo0 = __builtin_amdgcn_mfma_f32_32x32x16_bf16(v0, paf, oo0, 0,0,0);
        short8 v1 = *(const short8*)(Vc + (1*2+kb2)*512 + lane*8);
        oo1 = __builtin_amdgcn_mfma_f32_32x32x16_bf16(v1, paf, oo1, 0,0,0);
        __builtin_amdgcn_s_setprio(0);
      }
    }

    if (i < 15){
      asm volatile("s_waitcnt vmcnt(0)" ::: "memory");
    }
    __builtin_amdgcn_s_barrier();
    __builtin_amdgcn_sched_barrier(0);
  }

  // rowsum finalize: lane l and l^32 hold complementary key halves of the same q
  float osum = (os[0]+os[1]) + (os[2]+os[3]);
  osum += __shfl_xor(osum, 32);

  // ---- in-block merge of the two kv halves ----
  float* Of  = (float*)SHRAW;                 // [128][68]
  float* Os1 = (float*)(SHRAW + 128*68*4);    // [128]
  const int ql = qw*32 + l31;

  if (kvh == 1){
    #pragma unroll
    for (int g=0; g<4; ++g){
      f32x4 w0, w1;
      #pragma unroll
      for (int r=0;r<4;++r){ w0[r] = oo0[g*4+r]; w1[r] = oo1[g*4+r]; }
      int d0 = 8*g + 4*l5;
      *(f32x4*)(Of + ql*68 + d0)      = w0;
      *(f32x4*)(Of + ql*68 + d0 + 32) = w1;
    }
    Os1[ql] = osum;
  }
  __syncthreads();

  if (kvh == 0){
    const float rinv = 1.0f / (osum + Os1[ql]);
    if (mode == 0){
      #pragma unroll
      for (int r=0;r<16;++r){
        int d0 = (r&3) + 8*(r>>2) + 4*l5;
        float f0 = (oo0[r] + Of[ql*68 + d0])      * rinv;
        float f1 = (oo1[r] + Of[ql*68 + d0 + 32]) * rinv;
        ytb[base + (size_t)(d0)*SEQ + q0 + l31]    = f2bf(f0);
        ytb[base + (size_t)(d0+32)*SEQ + q0 + l31] = f2bf(f1);
      }
    } else {
      #pragma unroll
      for (int g=0; g<4; ++g){
        int d0 = 8*g + 4*l5;
        f32x4 w0 = *(const f32x4*)(Of + ql*68 + d0);
        f32x4 w1 = *(const f32x4*)(Of + ql*68 + d0 + 32);
        #pragma unroll
        for (int r=0;r<4;++r){ w0[r] = (w0[r]+oo0[g*4+r])*rinv; w1[r] = (w1[r]+oo1[g*4+r])*rinv; }
        *(f32x4*)(Of + ql*68 + d0)      = w0;
        *(f32x4*)(Of + ql*68 + d0 + 32) = w1;
      }
    }
  }

  if (mode == 1){
    __syncthreads();
    const int b = bh >> 4, h = bh & 15;
    const int qr = tid >> 2, dh = (tid & 3)*16;
    const float* src = Of + qr*68 + dh;
    float* drow = outf + ((size_t)(b*SEQ + qb*128 + qr))*DIM + h*HDIM + dh;
    #pragma unroll
    for (int k2=0;k2<4;++k2)
      *(float4*)(drow + k2*4) = *(const float4*)(src + k2*4);
  }
}

extern "C" void kernel_launch(void* const* d_in, const int* in_sizes, int n_in,
                              void* d_out, int out_size, void* d_ws, size_t ws_size,
                              hipStream_t stream) {
  const float* x   = (const float*)d_in[0];
  const float* x2  = (const float*)d_in[1];
  const float* Wq  = (const float*)d_in[2];
  const float* Wa  = (const float*)d_in[3];
  const float* Wkv = (const float*)d_in[4];
  float* out = (float*)d_out;

  unsigned short* ws = (unsigned short*)d_ws;
  unsigned short* xb   = ws;                      // 4096*1024
  unsigned short* x2b  = xb   + 4096*1024;
  unsigned short* Wqb  = x2b  + 4096*1024;        // 1024*1024
  unsigned short* Wab  = Wqb  + 1024*1024;
  unsigned short* Wkvb = Wab  + 1024*1024;        // 2048*1024
  unsigned short* Qw   = Wkvb + 2048*1024;        // BHND = 4194304 each
  unsigned short* Aw   = Qw   + 4194304;
  unsigned short* Kw   = Aw   + 4194304;
  unsigned short* Vwt  = Kw   + 4194304;          // V^T [bh][d][n] (direct from gemm)
  unsigned short* Ywt  = xb;                      // Y^T [bh][d][n] (xb dead after gemm)

  cast_all<<<dim3(3072), dim3(256), 0, stream>>>(x, x2, Wq, Wa, Wkv, ws);

  gemm_all<<<dim3(1024), dim3(256), 0, stream>>>(xb, x2b, Wqb, Wab, Wkvb, Qw, Aw, Kw, Vwt);

  // pass 1: Y^T = (softmax(A k^T s) v)^T  -- written directly transposed
  attn_pass<<<dim3(512), dim3(512), 0, stream>>>(Aw, Kw, Vwt, Ywt, nullptr, 0);

  // pass 2: out = softmax(q A^T s) Y
  attn_pass<<<dim3(512), dim3(512), 0, stream>>>(Qw, Aw, Ywt, nullptr, out, 1);
}